// Round 4
// baseline (99.256 us; speedup 1.0000x reference)
//
#include <hip/hip_runtime.h>
#include <hip/hip_bf16.h>

#define NTYPES 64
#define DIM 64
#define HB 64            // histogram/transpose blocks (one per type)

typedef short bf16x8 __attribute__((ext_vector_type(8)));
typedef float f32x4  __attribute__((ext_vector_type(4)));

static __device__ __forceinline__ short f2bf(float f) {
    __hip_bfloat16 h = __float2bfloat16(f);   // RNE
    return *reinterpret_cast<short*>(&h);
}

// ---------------- K1: per-block partial histogram + fused M transpose ----------------
// Block t: (a) partial histogram of types, (b) Mt[t][o][k] = bf16(M[t][k][o]).
__global__ void hist_mtr_k(const int* __restrict__ types, int n, int* __restrict__ part,
                           const float* __restrict__ M, short* __restrict__ Mt) {
    __shared__ int lh[NTYPES];
    int tid = threadIdx.x;
    int t = blockIdx.x;
    if (tid < NTYPES) lh[tid] = 0;
    __syncthreads();
    for (int i = t * blockDim.x + tid; i < n; i += gridDim.x * blockDim.x)
        atomicAdd(&lh[types[i]], 1);

    // transpose phase (no LDS needed; M is L2-resident, 1 MB total)
    {
        int o  = tid >> 2;          // 0..63 output index
        int ks = tid & 3;           // 16-k segment
        const float* Ms = M + ((size_t)t << 12);
        short vals[16];
        #pragma unroll
        for (int j = 0; j < 16; ++j)
            vals[j] = f2bf(Ms[(ks * 16 + j) * DIM + o]);
        short* dst = Mt + ((size_t)t << 12) + o * DIM + ks * 16;
        *(bf16x8*)(dst)     = *(const bf16x8*)(vals);
        *(bf16x8*)(dst + 8) = *(const bf16x8*)(vals + 8);
    }

    __syncthreads();
    if (tid < NTYPES) part[t * NTYPES + tid] = lh[tid];
}

// ---------------- K2: parallel reduce of partials + wave shfl-scan ----------------
__global__ void scan_k(const int* __restrict__ part, int* __restrict__ start,
                       int* __restrict__ cursor) {
    __shared__ int ps[4][NTYPES];
    int tid = threadIdx.x;
    int t = tid & 63, seg = tid >> 6;
    int s = 0;
    #pragma unroll
    for (int i = 0; i < HB / 4; ++i)
        s += part[(seg * (HB / 4) + i) * NTYPES + t];
    ps[seg][t] = s;
    __syncthreads();
    if (tid < 64) {
        int sum = ps[0][t] + ps[1][t] + ps[2][t] + ps[3][t];
        int inc = sum;
        #pragma unroll
        for (int d = 1; d < 64; d <<= 1) {
            int u = __shfl_up(inc, d);
            if (t >= d) inc += u;
        }
        int exc = inc - sum;
        start[t] = exc;
        cursor[t] = exc;
        if (t == 63) start[NTYPES] = inc;
    }
}

// ---------------- K3: block-aggregated scatter -> perm sorted by type ----------------
__global__ void scatter_k(const int* __restrict__ types, int n, int* __restrict__ cursor,
                          int* __restrict__ perm) {
    __shared__ int lh[NTYPES];
    __shared__ int lbase[NTYPES];
    int tid = threadIdx.x;
    if (tid < NTYPES) lh[tid] = 0;
    __syncthreads();
    const int PER = 4;
    int base = blockIdx.x * blockDim.x * PER;
    int myt[PER], myo[PER];
    #pragma unroll
    for (int k = 0; k < PER; ++k) {
        int i = base + k * blockDim.x + tid;
        if (i < n) {
            int t = types[i];
            myt[k] = t;
            myo[k] = atomicAdd(&lh[t], 1);
        } else {
            myt[k] = -1;
        }
    }
    __syncthreads();
    if (tid < NTYPES) lbase[tid] = lh[tid] ? atomicAdd(&cursor[tid], lh[tid]) : 0;
    __syncthreads();
    #pragma unroll
    for (int k = 0; k < PER; ++k)
        if (myt[k] >= 0)
            perm[lbase[myt[k]] + myo[k]] = base + k * blockDim.x + tid;
}

// ---------------- K4: MFMA grouped GEMM, LDS-free, barrier-free ----------------
// grid = (64 types, 26 slots), block = 256 (4 independent waves).
// Wave-tile = 16 atoms x 64 outs. Operands swapped vs R3:
//   A = Mt[t] fragment (lane: row o=ct*16+(l&15), k=(l>>4)*8+j) — 16B loads, L1-hot
//   B = x fragment     (lane: k=(l>>4)*8+j, col atom=l&15)      — 16B gathers
//   D[row=o][col=atom]: lane holds 4 CONSECUTIVE outs of one atom -> dwordx4 store.
__global__ __launch_bounds__(256) void main_k(const float* __restrict__ x,
                                              const short* __restrict__ Mt,
                                              const float* __restrict__ bias,
                                              const int* __restrict__ start,
                                              const int* __restrict__ perm,
                                              float* __restrict__ out) {
    int t = blockIdx.x;
    int s0 = start[t];
    int cnt = start[t + 1] - s0;
    if (cnt <= 0) return;

    int tid  = threadIdx.x;
    int lane = tid & 63;
    int wave = tid >> 6;
    int col  = lane & 15;     // atom within tile
    int hi   = lane >> 4;     // k-group / output sub-row

    const short* At = Mt + ((size_t)t << 12);
    int nt  = (cnt + 15) >> 4;
    int lim = s0 + cnt;

    for (int tau = blockIdx.y * 4 + wave; tau < nt; tau += gridDim.y * 4) {
        int abase = s0 + (tau << 4);
        int aidx  = abase + col;
        bool valid = aidx < lim;
        if (!valid) aidx = lim - 1;       // clamped read, store guarded
        int g = perm[aidx];

        // ---- B fragments: this lane's atom row of x, bf16 ----
        const float* xr = x + ((size_t)g << 6);
        float4 p0 = *(const float4*)(xr + hi * 8);
        float4 p1 = *(const float4*)(xr + hi * 8 + 4);
        float4 p2 = *(const float4*)(xr + 32 + hi * 8);
        float4 p3 = *(const float4*)(xr + 32 + hi * 8 + 4);
        bf16x8 b0, b1;
        b0[0] = f2bf(p0.x); b0[1] = f2bf(p0.y); b0[2] = f2bf(p0.z); b0[3] = f2bf(p0.w);
        b0[4] = f2bf(p1.x); b0[5] = f2bf(p1.y); b0[6] = f2bf(p1.z); b0[7] = f2bf(p1.w);
        b1[0] = f2bf(p2.x); b1[1] = f2bf(p2.y); b1[2] = f2bf(p2.z); b1[3] = f2bf(p2.w);
        b1[4] = f2bf(p3.x); b1[5] = f2bf(p3.y); b1[6] = f2bf(p3.z); b1[7] = f2bf(p3.w);

        // ---- 4 output-tiles x 2 K-halves; acc seeded with bias ----
        f32x4 acc[4];
        #pragma unroll
        for (int ct = 0; ct < 4; ++ct) {
            const short* ar = At + (ct * 16 + col) * DIM + hi * 8;
            bf16x8 a0 = *(const bf16x8*)(ar);
            bf16x8 a1 = *(const bf16x8*)(ar + 32);
            acc[ct] = *(const f32x4*)(bias + t * DIM + ct * 16 + hi * 4);
            acc[ct] = __builtin_amdgcn_mfma_f32_16x16x32_bf16(a0, b0, acc[ct], 0, 0, 0);
            acc[ct] = __builtin_amdgcn_mfma_f32_16x16x32_bf16(a1, b1, acc[ct], 0, 0, 0);
        }

        // ---- store: 4 x dwordx4, contiguous 16B per lane ----
        if (valid) {
            float* orow = out + ((size_t)g << 6);
            #pragma unroll
            for (int ct = 0; ct < 4; ++ct)
                *(f32x4*)(orow + ct * 16 + hi * 4) = acc[ct];
        }
    }
}

extern "C" void kernel_launch(void* const* d_in, const int* in_sizes, int n_in,
                              void* d_out, int out_size, void* d_ws, size_t ws_size,
                              hipStream_t stream) {
    const float* x     = (const float*)d_in[0];
    const int*   types = (const int*)d_in[1];
    const float* M     = (const float*)d_in[2];
    const float* bias  = (const float*)d_in[3];
    float* out = (float*)d_out;
    int n = in_sizes[1];

    // ws (ints): part[64*64] | start[65] | cursor[64] | pad->4352 | perm[n] | Mt (bf16)
    int* part   = (int*)d_ws;
    int* start  = part + HB * NTYPES;
    int* cursor = start + 65;
    int* perm   = part + HB * NTYPES + 256;          // 16B-aligned (17408 B)
    short* Mt   = (short*)(perm + ((n + 3) & ~3));   // 512 KB, 16B-aligned for n%4==0

    hist_mtr_k<<<HB, 256, 0, stream>>>(types, n, part, M, Mt);
    scan_k<<<1, 256, 0, stream>>>(part, start, cursor);
    scatter_k<<<(n + 1023) / 1024, 256, 0, stream>>>(types, n, cursor, perm);
    main_k<<<dim3(NTYPES, 26), 256, 0, stream>>>(x, Mt, bias, start, perm, out);
}